// Round 7
// baseline (116.650 us; speedup 1.0000x reference)
//
#include <hip/hip_runtime.h>

// BatchIndependentLoss: SupCon-style loss, B=2048, V=2, D=256, N=4096.
// loss = -mean_i( lp_i - (W_i - e^{lp}*lp) / u_new[i%B] )
// Structure: NO LDS/barriers in GEMM K-loop; 2 MB frag-major bf16 operand
// (L2-resident); one wave = one 64x64 upper-triangle tile (2080 tiles);
// row+col (transposed) stats from each tile; separate tiny finalize
// dispatch (R6: per-block __threadfence ticket was L2-writeback-bound).
// R7: latency attack -- R6 gemm inferred ~25-30 us vs ~7 us pipe floors
// (2 waves/SIMD, depth-1 prefetch exposed ~200cyc L2 latency per k-step).
//   (a) TPB=1: 64-thread blocks, 2080 blocks -> finer scheduling, no
//       4-wave tail quantization;
//   (b) prefetch depth 2 (3 rotating frag buffers) -> 2 k-steps of loads
//       in flight, MFMA never waits on a just-issued load.
//
// CmF layout: shorts, index = ((band*8 + k)*4 + rt)*512 + (l15*4+quad)*8 + j
// Fragment load for (band, k, rt): wave reads one contiguous 1 KB chunk.

#define BSZ   2048
#define NROW  4096
#define DDIM  256
#define INVT  (1.0f / 0.07f)
#define NB64  64                       // 4096/64 bands
#define NT2   (NB64 * (NB64 + 1) / 2)  // 2080 upper-triangle 64x64 tiles

typedef __attribute__((ext_vector_type(8))) __bf16 bf16x8;
typedef __attribute__((ext_vector_type(4))) float f32x4;

__device__ __forceinline__ short f2bs(float x) {
    __bf16 b = (__bf16)x;
    return __builtin_bit_cast(short, b);
}

// contrast row i = v*B + b  ->  features row b*V + v  (fp32, 256 elems)
__device__ __forceinline__ const float* crow_ptr(const float* feats, int i) {
    return feats + (((i & (BSZ - 1)) * 2 + (i >> 11)) << 8);
}

// ---------------- prep: frag-major bf16 pack, self-dots, zero E/W ----------
__global__ __launch_bounds__(256) void prep_kernel(const float* __restrict__ feats,
        float* __restrict__ selfdot, float* __restrict__ EWzero,
        short* __restrict__ CmF) {
    int tid = threadIdx.x;
    int z = blockIdx.x * 256 + tid;
    if (z < 2 * NROW) EWzero[z] = 0.0f;                  // zero E and W

    // --- part A: self-dot, one wave per row (1024 blocks x 4 waves) ---
    int lane = tid & 63;
    int row  = (blockIdx.x << 2) + (tid >> 6);
    const float4* src = (const float4*)crow_ptr(feats, row);
    float4 v = src[lane];
    float a0 = (float)(__bf16)v.x, a1 = (float)(__bf16)v.y;
    float a2 = (float)(__bf16)v.z, a3 = (float)(__bf16)v.w;
    float s = a0 * a0 + a1 * a1 + a2 * a2 + a3 * a3;     // self-dot of bf16 row
    #pragma unroll
    for (int off = 32; off; off >>= 1) s += __shfl_xor(s, off, 64);
    if (lane == 0) selfdot[row] = s;

    // --- part B: fragment-major pack; gid covers 2M shorts / 8 per thread ---
    int gid  = z;                    // 0..262143
    int quad = gid & 3;
    int l15  = (gid >> 2) & 15;
    int rt   = (gid >> 6) & 3;
    int k    = (gid >> 8) & 7;
    int b    = gid >> 12;
    int srow = (b << 6) + (rt << 4) + l15;
    int kel  = (k << 5) + (quad << 3);
    const float4* fp = (const float4*)(crow_ptr(feats, srow) + kel);
    float4 v0 = fp[0], v1 = fp[1];
    short h[8] = { f2bs(v0.x), f2bs(v0.y), f2bs(v0.z), f2bs(v0.w),
                   f2bs(v1.x), f2bs(v1.y), f2bs(v1.z), f2bs(v1.w) };
    *(int4*)(CmF + gid * 8) = *(int4*)h;
}

// ---------------- barrier-free symmetric GEMM + stats ----------------------
// One 64-thread block == one wave == one 64x64 tile. Depth-2 prefetch.
__global__ __launch_bounds__(64, 2) void gemm_sym(const short* __restrict__ CmF,
        const float* __restrict__ selfdot, float* __restrict__ E,
        float* __restrict__ W, float* __restrict__ Lpos) {
    int lane = threadIdx.x;          // 0..63
    int quad = lane >> 4;
    int l15  = lane & 15;

    // triangle decode t -> (p,q), p>=q
    int t = blockIdx.x;
    int p = (int)((sqrtf(8.0f * (float)t + 1.0f) - 1.0f) * 0.5f);
    while ((p + 1) * (p + 2) / 2 <= t) ++p;
    while (p * (p + 1) / 2 > t) --p;
    int q = t - p * (p + 1) / 2;
    int rowBase = q << 6;            // row band (64)
    int colBase = p << 6;            // col band, >= row band
    bool offdiag = (p != q);

    const short* aB = CmF + q * 16384 + ((l15 << 2) + quad) * 8;
    const short* bB = CmF + p * 16384 + ((l15 << 2) + quad) * 8;

    f32x4 acc[4][4];
    #pragma unroll
    for (int a = 0; a < 4; ++a)
        #pragma unroll
        for (int c = 0; c < 4; ++c) acc[a][c] = (f32x4){0.f, 0.f, 0.f, 0.f};

    // depth-2 software pipeline: 3 rotating fragment buffers
    bf16x8 aF[3][4], bF[3][4];
    #pragma unroll
    for (int rt = 0; rt < 4; ++rt) {
        aF[0][rt] = *(const bf16x8*)(aB + (0 * 4 + rt) * 512);
        bF[0][rt] = *(const bf16x8*)(bB + (0 * 4 + rt) * 512);
    }
    #pragma unroll
    for (int rt = 0; rt < 4; ++rt) {
        aF[1][rt] = *(const bf16x8*)(aB + (1 * 4 + rt) * 512);
        bF[1][rt] = *(const bf16x8*)(bB + (1 * 4 + rt) * 512);
    }

    #pragma unroll
    for (int k = 0; k < 8; ++k) {
        int cur = k % 3;
        int nxt = (k + 2) % 3;
        if (k < 6) {                 // issue loads for step k+2 (2 steps ahead)
            #pragma unroll
            for (int rt = 0; rt < 4; ++rt) {
                aF[nxt][rt] = *(const bf16x8*)(aB + ((k + 2) * 4 + rt) * 512);
                bF[nxt][rt] = *(const bf16x8*)(bB + ((k + 2) * 4 + rt) * 512);
            }
        }
        #pragma unroll
        for (int rt = 0; rt < 4; ++rt)
            #pragma unroll
            for (int ct = 0; ct < 4; ++ct)
                acc[rt][ct] = __builtin_amdgcn_mfma_f32_16x16x32_bf16(
                    aF[cur][rt], bF[cur][ct], acc[rt][ct], 0, 0, 0);
    }

    // ---- epilogue: C/D layout col = lane&15, row = quad*4 + reg  [m89/m91]
    float sdr[4][4];
    #pragma unroll
    for (int rt = 0; rt < 4; ++rt)
        #pragma unroll
        for (int r = 0; r < 4; ++r)
            sdr[rt][r] = selfdot[rowBase + rt * 16 + (quad << 2) + r];
    float sdc[4];
    #pragma unroll
    for (int ct = 0; ct < 4; ++ct)
        sdc[ct] = selfdot[colBase + ct * 16 + l15];

    float Ep[4][4] = {}, Wp[4][4] = {};
    float Ec[4] = {}, Wc[4] = {};
    #pragma unroll
    for (int rt = 0; rt < 4; ++rt) {
        #pragma unroll
        for (int ct = 0; ct < 4; ++ct) {
            int gcol = colBase + ct * 16 + l15;
            #pragma unroll
            for (int r = 0; r < 4; ++r) {
                int grow = rowBase + rt * 16 + (quad << 2) + r;
                float d = acc[rt][ct][r];
                float l = (d - sdr[rt][r]) * INVT;       // row-view logit
                float e = __expf(l);
                Ep[rt][r] += e;
                Wp[rt][r] += e * l;
                if (gcol == (grow ^ BSZ)) Lpos[grow] = l;
                if (offdiag) {
                    float l2 = (d - sdc[ct]) * INVT;     // col-view logit
                    float e2 = __expf(l2);
                    Ec[ct] += e2;
                    Wc[ct] += e2 * l2;
                    if (grow == (gcol ^ BSZ)) Lpos[gcol] = l2;
                }
            }
        }
    }
    // row-path: reduce over 16 l15 lanes per row, 1-lane atomic per row
    #pragma unroll
    for (int rt = 0; rt < 4; ++rt) {
        #pragma unroll
        for (int r = 0; r < 4; ++r) {
            float e = Ep[rt][r], w = Wp[rt][r];
            #pragma unroll
            for (int off = 1; off < 16; off <<= 1) {
                e += __shfl_xor(e, off, 64);
                w += __shfl_xor(w, off, 64);
            }
            if (l15 == 0) {
                int grow = rowBase + rt * 16 + (quad << 2) + r;
                atomicAdd(&E[grow], e);
                atomicAdd(&W[grow], w);
            }
        }
    }
    // col-path: reduce over 4 quads per col, 16-lane atomic
    if (offdiag) {
        #pragma unroll
        for (int ct = 0; ct < 4; ++ct) {
            float e = Ec[ct], w = Wc[ct];
            e += __shfl_xor(e, 16, 64);  w += __shfl_xor(w, 16, 64);
            e += __shfl_xor(e, 32, 64);  w += __shfl_xor(w, 32, 64);
            if (quad == 0) {
                int gcol = colBase + ct * 16 + l15;
                atomicAdd(&E[gcol], e);
                atomicAdd(&W[gcol], w);
            }
        }
    }
}

// ---------------- finalize: u_new + scalar reduction -----------------------
__global__ __launch_bounds__(1024) void finalize_kernel(const int* __restrict__ index,
        const float* __restrict__ u, const float* __restrict__ E,
        const float* __restrict__ W, const float* __restrict__ Lpos,
        float* __restrict__ out) {
    __shared__ float unew[BSZ];
    __shared__ float partial[16];
    int tid = threadIdx.x;
    for (int b = tid; b < BSZ; b += 1024) {
        float lp = Lpos[b];
        unew[b] = 0.1f * u[index[b]] + 0.9f * (E[b] - __expf(lp));
    }
    __syncthreads();
    float local = 0.0f;
    for (int i = tid; i < NROW; i += 1024) {
        float lp  = Lpos[i];
        float elp = __expf(lp);
        local += lp - (W[i] - elp * lp) / unew[i & (BSZ - 1)];
    }
    #pragma unroll
    for (int off = 32; off; off >>= 1) local += __shfl_xor(local, off, 64);
    if ((tid & 63) == 0) partial[tid >> 6] = local;
    __syncthreads();
    if (tid == 0) {
        float s = 0.0f;
        #pragma unroll
        for (int w = 0; w < 16; ++w) s += partial[w];
        out[0] = -s / (float)NROW;
    }
}

extern "C" void kernel_launch(void* const* d_in, const int* in_sizes, int n_in,
                              void* d_out, int out_size, void* d_ws, size_t ws_size,
                              hipStream_t stream) {
    const int*   index = (const int*)d_in[0];
    const float* feats = (const float*)d_in[1];
    const float* u     = (const float*)d_in[2];
    float* out = (float*)d_out;

    // ws: [selfdot|E|W|Lpos] (4x4096 f32 = 64 KB) | ... | CmF @128KB (2 MB)
    float* selfdot = (float*)d_ws;
    float* E    = selfdot + NROW;
    float* W    = E + NROW;
    float* Lpos = W + NROW;
    short* CmF  = (short*)((char*)d_ws + 131072);

    prep_kernel<<<1024, 256, 0, stream>>>(feats, selfdot, E, CmF);
    gemm_sym<<<NT2, 64, 0, stream>>>(CmF, selfdot, E, W, Lpos);
    finalize_kernel<<<1, 1024, 0, stream>>>(index, u, E, W, Lpos, out);
}

// Round 8
// 115.974 us; speedup vs baseline: 1.0058x; 1.0058x over previous
//
#include <hip/hip_runtime.h>

// BatchIndependentLoss: SupCon-style loss, B=2048, V=2, D=256, N=4096.
// loss = -mean_i( lp_i - (W_i - e^{lp}*lp) / u_new[i%B] )
// Structure: barrier-free symmetric GEMM (one wave = one 64x64 upper-tri
// tile, 2080 tiles, frag-major 2 MB bf16 operand in L2) + fused row/col
// stats + tiny finalize dispatch.
// R8: epilogue-arithmetic attack. R3/R6/R7 all pinned gemm at ~30 us
// across 3 different load structures => bound is the shared epilogue VALU
// (33.5M exp chains ~27 us). Changes:
//  (a) exp2-domain: prep stores msd=-sd*c1 (c1=log2e/T); per view the
//      chain is fma + v_exp2 + add + fma (10 cyc vs ~16). W,lp recovered
//      by one *ln2 in finalize (everything is linear in W and lp).
//  (b) Lpos hoisted: positives j=i^2048 only occur in tiles p==q^32
//      (32 of 2080) -> per-element compares removed from the hot loop.
//
// CmF layout: shorts, index = ((band*8 + k)*4 + rt)*512 + (l15*4+quad)*8 + j
// Fragment load for (band, k, rt): wave reads one contiguous 1 KB chunk.

#define BSZ   2048
#define NROW  4096
#define DDIM  256
#define NB64  64                       // 4096/64 bands
#define NT2   (NB64 * (NB64 + 1) / 2)  // 2080 upper-triangle 64x64 tiles
#define C1    (1.4426950408889634f / 0.07f)   // log2(e)/TEMPERATURE
#define LN2   0.6931471805599453f

typedef __attribute__((ext_vector_type(8))) __bf16 bf16x8;
typedef __attribute__((ext_vector_type(4))) float f32x4;

__device__ __forceinline__ short f2bs(float x) {
    __bf16 b = (__bf16)x;
    return __builtin_bit_cast(short, b);
}

// contrast row i = v*B + b  ->  features row b*V + v  (fp32, 256 elems)
__device__ __forceinline__ const float* crow_ptr(const float* feats, int i) {
    return feats + (((i & (BSZ - 1)) * 2 + (i >> 11)) << 8);
}

// ---------------- prep: frag-major bf16 pack, -sd*c1, zero E/W -------------
__global__ __launch_bounds__(256) void prep_kernel(const float* __restrict__ feats,
        float* __restrict__ msd, float* __restrict__ EWzero,
        short* __restrict__ CmF) {
    int tid = threadIdx.x;
    int z = blockIdx.x * 256 + tid;
    if (z < 2 * NROW) EWzero[z] = 0.0f;                  // zero E and W

    // --- part A: self-dot, one wave per row (1024 blocks x 4 waves) ---
    int lane = tid & 63;
    int row  = (blockIdx.x << 2) + (tid >> 6);
    const float4* src = (const float4*)crow_ptr(feats, row);
    float4 v = src[lane];
    float a0 = (float)(__bf16)v.x, a1 = (float)(__bf16)v.y;
    float a2 = (float)(__bf16)v.z, a3 = (float)(__bf16)v.w;
    float s = a0 * a0 + a1 * a1 + a2 * a2 + a3 * a3;     // self-dot of bf16 row
    #pragma unroll
    for (int off = 32; off; off >>= 1) s += __shfl_xor(s, off, 64);
    if (lane == 0) msd[row] = -s * C1;                   // pre-scaled for fma

    // --- part B: fragment-major pack; gid covers 2M shorts / 8 per thread ---
    int gid  = z;                    // 0..262143
    int quad = gid & 3;
    int l15  = (gid >> 2) & 15;
    int rt   = (gid >> 6) & 3;
    int k    = (gid >> 8) & 7;
    int b    = gid >> 12;
    int srow = (b << 6) + (rt << 4) + l15;
    int kel  = (k << 5) + (quad << 3);
    const float4* fp = (const float4*)(crow_ptr(feats, srow) + kel);
    float4 v0 = fp[0], v1 = fp[1];
    short h[8] = { f2bs(v0.x), f2bs(v0.y), f2bs(v0.z), f2bs(v0.w),
                   f2bs(v1.x), f2bs(v1.y), f2bs(v1.z), f2bs(v1.w) };
    *(int4*)(CmF + gid * 8) = *(int4*)h;
}

// ---------------- barrier-free symmetric GEMM + stats ----------------------
// One 64-thread block == one wave == one 64x64 tile. Depth-2 prefetch.
// All logits kept in exp2 domain: t = d*C1 + msd;  e = exp2(t);
// E += e; W2 += e*t  (W = W2*ln2 recovered in finalize).
__global__ __launch_bounds__(64, 2) void gemm_sym(const short* __restrict__ CmF,
        const float* __restrict__ msd, float* __restrict__ E,
        float* __restrict__ W2, float* __restrict__ Lpos) {
    int lane = threadIdx.x;          // 0..63
    int quad = lane >> 4;
    int l15  = lane & 15;

    // triangle decode t -> (p,q), p>=q
    int t = blockIdx.x;
    int p = (int)((sqrtf(8.0f * (float)t + 1.0f) - 1.0f) * 0.5f);
    while ((p + 1) * (p + 2) / 2 <= t) ++p;
    while (p * (p + 1) / 2 > t) --p;
    int q = t - p * (p + 1) / 2;
    int rowBase = q << 6;            // row band (64)
    int colBase = p << 6;            // col band, >= row band
    bool offdiag = (p != q);

    const short* aB = CmF + q * 16384 + ((l15 << 2) + quad) * 8;
    const short* bB = CmF + p * 16384 + ((l15 << 2) + quad) * 8;

    f32x4 acc[4][4];
    #pragma unroll
    for (int a = 0; a < 4; ++a)
        #pragma unroll
        for (int c = 0; c < 4; ++c) acc[a][c] = (f32x4){0.f, 0.f, 0.f, 0.f};

    // depth-2 software pipeline: 3 rotating fragment buffers
    bf16x8 aF[3][4], bF[3][4];
    #pragma unroll
    for (int rt = 0; rt < 4; ++rt) {
        aF[0][rt] = *(const bf16x8*)(aB + (0 * 4 + rt) * 512);
        bF[0][rt] = *(const bf16x8*)(bB + (0 * 4 + rt) * 512);
    }
    #pragma unroll
    for (int rt = 0; rt < 4; ++rt) {
        aF[1][rt] = *(const bf16x8*)(aB + (1 * 4 + rt) * 512);
        bF[1][rt] = *(const bf16x8*)(bB + (1 * 4 + rt) * 512);
    }

    #pragma unroll
    for (int k = 0; k < 8; ++k) {
        int cur = k % 3;
        int nxt = (k + 2) % 3;
        if (k < 6) {                 // issue loads for step k+2 (2 steps ahead)
            #pragma unroll
            for (int rt = 0; rt < 4; ++rt) {
                aF[nxt][rt] = *(const bf16x8*)(aB + ((k + 2) * 4 + rt) * 512);
                bF[nxt][rt] = *(const bf16x8*)(bB + ((k + 2) * 4 + rt) * 512);
            }
        }
        #pragma unroll
        for (int rt = 0; rt < 4; ++rt)
            #pragma unroll
            for (int ct = 0; ct < 4; ++ct)
                acc[rt][ct] = __builtin_amdgcn_mfma_f32_16x16x32_bf16(
                    aF[cur][rt], bF[cur][ct], acc[rt][ct], 0, 0, 0);
    }

    // ---- epilogue: C/D layout col = lane&15, row = quad*4 + reg  [m89/m91]
    float msdr[4][4];                // -sd(row)*C1
    #pragma unroll
    for (int rt = 0; rt < 4; ++rt)
        #pragma unroll
        for (int r = 0; r < 4; ++r)
            msdr[rt][r] = msd[rowBase + rt * 16 + (quad << 2) + r];
    float msdc[4];                   // -sd(col)*C1, lane-varying via l15
    #pragma unroll
    for (int ct = 0; ct < 4; ++ct)
        msdc[ct] = msd[colBase + ct * 16 + l15];

    float Ep[4][4] = {}, Wp[4][4] = {};
    float Ec[4] = {}, Wc[4] = {};
    #pragma unroll
    for (int rt = 0; rt < 4; ++rt) {
        #pragma unroll
        for (int ct = 0; ct < 4; ++ct) {
            #pragma unroll
            for (int r = 0; r < 4; ++r) {
                float d = acc[rt][ct][r];
                float tt = __builtin_fmaf(d, C1, msdr[rt][r]);   // row-view log2
                float e = __builtin_exp2f(tt);
                Ep[rt][r] += e;
                Wp[rt][r] = __builtin_fmaf(e, tt, Wp[rt][r]);
                if (offdiag) {
                    float t2 = __builtin_fmaf(d, C1, msdc[ct]);  // col-view log2
                    float e2 = __builtin_exp2f(t2);
                    Ec[ct] += e2;
                    Wc[ct] = __builtin_fmaf(e2, t2, Wc[ct]);
                }
            }
        }
    }

    // ---- Lpos: only tiles with p == q^32 contain positives (j = i^2048)
    if (p == (q ^ 32)) {
        // positive at ct==rt, lane with l15 == (quad<<2)+r
        if (quad == (l15 >> 2)) {
            int r = l15 & 3;
            #pragma unroll
            for (int rt = 0; rt < 4; ++rt) {
                float d = acc[rt][rt][r];
                Lpos[rowBase + rt * 16 + l15] = __builtin_fmaf(d, C1, msdr[rt][r]);
                Lpos[colBase + rt * 16 + l15] = __builtin_fmaf(d, C1, msdc[rt]);
            }
        }
    }

    // row-path: reduce over 16 l15 lanes per row, 1-lane atomic per row
    #pragma unroll
    for (int rt = 0; rt < 4; ++rt) {
        #pragma unroll
        for (int r = 0; r < 4; ++r) {
            float e = Ep[rt][r], w = Wp[rt][r];
            #pragma unroll
            for (int off = 1; off < 16; off <<= 1) {
                e += __shfl_xor(e, off, 64);
                w += __shfl_xor(w, off, 64);
            }
            if (l15 == 0) {
                int grow = rowBase + rt * 16 + (quad << 2) + r;
                atomicAdd(&E[grow], e);
                atomicAdd(&W2[grow], w);
            }
        }
    }
    // col-path: reduce over 4 quads per col, 16-lane atomic
    if (offdiag) {
        #pragma unroll
        for (int ct = 0; ct < 4; ++ct) {
            float e = Ec[ct], w = Wc[ct];
            e += __shfl_xor(e, 16, 64);  w += __shfl_xor(w, 16, 64);
            e += __shfl_xor(e, 32, 64);  w += __shfl_xor(w, 32, 64);
            if (quad == 0) {
                int gcol = colBase + ct * 16 + l15;
                atomicAdd(&E[gcol], e);
                atomicAdd(&W2[gcol], w);
            }
        }
    }
}

// ---------------- finalize: u_new + scalar reduction (exp2 domain) ---------
__global__ __launch_bounds__(1024) void finalize_kernel(const int* __restrict__ index,
        const float* __restrict__ u, const float* __restrict__ E,
        const float* __restrict__ W2, const float* __restrict__ Lpos,
        float* __restrict__ out) {
    __shared__ float unew[BSZ];
    __shared__ float partial[16];
    int tid = threadIdx.x;
    for (int b = tid; b < BSZ; b += 1024) {
        float tp = Lpos[b];
        unew[b] = 0.1f * u[index[b]] + 0.9f * (E[b] - __builtin_exp2f(tp));
    }
    __syncthreads();
    float local = 0.0f;
    for (int i = tid; i < NROW; i += 1024) {
        float tp  = Lpos[i];
        float etp = __builtin_exp2f(tp);
        local += tp - (W2[i] - etp * tp) / unew[i & (BSZ - 1)];
    }
    #pragma unroll
    for (int off = 32; off; off >>= 1) local += __shfl_xor(local, off, 64);
    if ((tid & 63) == 0) partial[tid >> 6] = local;
    __syncthreads();
    if (tid == 0) {
        float s = 0.0f;
        #pragma unroll
        for (int w = 0; w < 16; ++w) s += partial[w];
        out[0] = -LN2 * s / (float)NROW;   // exp2-domain -> nat-log domain
    }
}

extern "C" void kernel_launch(void* const* d_in, const int* in_sizes, int n_in,
                              void* d_out, int out_size, void* d_ws, size_t ws_size,
                              hipStream_t stream) {
    const int*   index = (const int*)d_in[0];
    const float* feats = (const float*)d_in[1];
    const float* u     = (const float*)d_in[2];
    float* out = (float*)d_out;

    // ws: [msd|E|W2|Lpos] (4x4096 f32 = 64 KB) | ... | CmF @128KB (2 MB)
    float* msd  = (float*)d_ws;
    float* E    = msd + NROW;
    float* W2   = E + NROW;
    float* Lpos = W2 + NROW;
    short* CmF  = (short*)((char*)d_ws + 131072);

    prep_kernel<<<1024, 256, 0, stream>>>(feats, msd, E, CmF);
    gemm_sym<<<NT2, 64, 0, stream>>>(CmF, msd, E, W2, Lpos);
    finalize_kernel<<<1, 1024, 0, stream>>>(index, u, E, W2, Lpos, out);
}